// Round 10
// baseline (422.565 us; speedup 1.0000x reference)
//
#include <hip/hip_runtime.h>
#include <stdint.h>

// CIN (xDeepFM) forward, MI355X f16-MFMA implementation. Round 10:
//  - W-LDS path DELETED: B-fragments load directly global->VGPR
//    (global_load_dwordx4, double-buffered frA/frB, issued one tile ahead).
//    No wtile, no gload_lds, no XOR swizzle, no K-loop syncs at all.
//    LDS = x0pk only (10.5KB). Rationale: r7/r8/r9 all pinned at ~42%
//    MfmaUtil; per-tile LDS busy (~1000cy: W write+read+xs) vs MFMA 1242cy
//    was the co-limiter. Per-lane W need is only 64B/tile -> regs suffice.
//  - shell = r8-proven: 512 blocks x 512 thr, M=64 (2 samples), 8 waves =
//    8 N-groups of 32 cols, 2 blocks/CU = 4 waves/SIMD, launch_bounds(512,4).
//  - h-fragments direct-from-global (r8-proven), layer-0 extract from x0pk
//    (r8-proven). Epilogue/fsum/prep/finalize verbatim r8.
// Layers: out[b,d,o] = relu(bias[o] + sum_{f,h'} x0[b,f,d]*h[b,h',d]*W[f*Hp+h',o])
//   layer0: Hp=39 (pad 64), layers1/2: Hp=128. B=1024, F=39, D=32, N=256.

typedef unsigned int u32;
typedef unsigned short u16;
typedef __attribute__((ext_vector_type(8))) unsigned short us8;
typedef __attribute__((ext_vector_type(8))) _Float16 half8;
typedef __attribute__((ext_vector_type(4))) float f32x4;

__device__ __forceinline__ u16 f32_to_f16u(float f) {
  union { _Float16 h; u16 u; } c;
  c.h = (_Float16)f;
  return c.u;
}
__device__ __forceinline__ u32 pkmul(u32 a, u32 b) {
  u32 r;
  asm("v_pk_mul_f16 %0, %1, %2" : "=v"(r) : "v"(a), "v"(b));
  return r;
}

// ---------------- prep: W (K,256) f32 -> WT (256, KPAD) f16, transposed ------
__global__ void prep_wt(const float* __restrict__ W0, const float* __restrict__ W1,
                        const float* __restrict__ W2, u16* __restrict__ WT0,
                        u16* __restrict__ WT1, u16* __restrict__ WT2) {
  int blk = blockIdx.x;
  const float* W;
  u16* WT;
  int KPAD, kp0;
  bool l0 = false;
  if (blk < 312) { W = W0; WT = WT0; KPAD = 2496; kp0 = blk * 8; l0 = true; }
  else if (blk < 936) { W = W1; WT = WT1; KPAD = 4992; kp0 = (blk - 312) * 8; }
  else { W = W2; WT = WT2; KPAD = 4992; kp0 = (blk - 936) * 8; }

  __shared__ u16 lds[8][257];
  int t = threadIdx.x;  // 256 = n
  #pragma unroll
  for (int kk = 0; kk < 8; ++kk) {
    int kp = kp0 + kk;
    float v;
    if (l0) {
      int f = kp >> 6, hh = kp & 63;
      v = (hh < 39) ? W[(f * 39 + hh) * 256 + t] : 0.f;
    } else {
      v = W[kp * 256 + t];
    }
    lds[kk][t] = f32_to_f16u(v);
  }
  __syncthreads();
  us8 o;
  #pragma unroll
  for (int kk = 0; kk < 8; ++kk) o[kk] = lds[kk][t];
  *(us8*)(&WT[(size_t)t * KPAD + kp0]) = o;
}

// ---------------- main layer kernel ------------------------------------------
// grid 512 x 512 threads. Block: 2 samples (M=64 rows), 8 waves each covering
// all 64 rows x its own 32-col slice. B direct-to-reg dbuf; no K-loop syncs.
template <int LAYER>
__global__ __launch_bounds__(512, 4) void cin_layer(
    const float* __restrict__ x, const u16* __restrict__ hin,
    const u16* __restrict__ WT, const float* __restrict__ bias,
    u16* __restrict__ hout, float* __restrict__ fsum) {
  constexpr int HPAD = (LAYER == 0) ? 64 : 128;
  constexpr int KPAD = 39 * HPAD;
  constexpr int HC2 = HPAD / 64;  // k64 tiles per f
  constexpr int NT = 39 * HC2;

  __shared__ u32 x0pk[2][32][41];  // (x,x) packed f16 pairs

  const int tid = threadIdx.x;
  const int bbase = blockIdx.x * 2;

  // ---- stage x -> x0pk
  for (int idx = tid; idx < 2 * 1248; idx += 512) {
    int b = idx / 1248;
    int rem = idx - b * 1248;
    int f = rem >> 5, d = rem & 31;
    u16 xh = f32_to_f16u(x[(bbase + b) * 1248 + rem]);
    x0pk[b][d][f] = (u32)xh | ((u32)xh << 16);
  }

  const int lane = tid & 63;
  const int w = tid >> 6;  // wave 0..7 -> 32-col slice
  const int l15 = lane & 15;
  const int g = lane >> 4;

  int rs[4], rd[4];  // per m-tile: sample and d for this lane's A-row
  #pragma unroll
  for (int m = 0; m < 4; ++m) {
    int row = m * 16 + l15;
    rs[m] = row >> 5;
    rd[m] = row & 31;
  }

  // Direct global B pointers: rows n0 = w*32 + l15 (nt=0), n1 = n0+16 (nt=1);
  // per-lane 16B chunk at k-offset g*8. Same per-lane k-map as A => layout-safe.
  const u16* wp0 = WT + (size_t)(w * 32 + l15) * KPAD + g * 8;
  const u16* wp1 = wp0 + (size_t)16 * KPAD;

  f32x4 acc[4][2];
  #pragma unroll
  for (int m = 0; m < 4; ++m)
    #pragma unroll
    for (int n = 0; n < 2; ++n) acc[m][n] = (f32x4){0.f, 0.f, 0.f, 0.f};

  __syncthreads();  // x0pk ready for all waves

  union HF { u32 u[4]; half8 h; us8 s; };
  HF hf2[4][2];  // h fragments for current k64 chunk (reused across 39 f)
  if (LAYER == 0) {
    #pragma unroll
    for (int m = 0; m < 4; ++m)
      #pragma unroll
      for (int c = 0; c < 2; ++c)
        #pragma unroll
        for (int i = 0; i < 4; ++i) {
          int h0 = c * 32 + g * 8 + 2 * i;
          u32 lo = (h0 < 39) ? (x0pk[rs[m]][rd[m]][h0] & 0xffffu) : 0u;
          u32 hi = (h0 + 1 < 39) ? (x0pk[rs[m]][rd[m]][h0 + 1] & 0xffffu) : 0u;
          hf2[m][c].u[i] = lo | (hi << 16);
        }
  } else {
    #pragma unroll
    for (int m = 0; m < 4; ++m)
      #pragma unroll
      for (int c = 0; c < 2; ++c)
        hf2[m][c].s = *(const us8*)(
            &hin[(((size_t)(bbase + rs[m]) * 32 + rd[m]) << 7) + c * 32 + g * 8]);
  }

  // preload tile 0 fragments + xs
  HF frA[2][2], frB[2][2];
  u32 xsA[4], xsB[4];
  #pragma unroll
  for (int c = 0; c < 2; ++c) {
    frA[c][0].s = *(const us8*)(wp0 + c * 32);
    frA[c][1].s = *(const us8*)(wp1 + c * 32);
  }
  #pragma unroll
  for (int m = 0; m < 4; ++m) xsA[m] = x0pk[rs[m]][rd[m]][0];

  int f = 0, hc = 0;
  auto tile = [&](HF(&cur)[2][2], HF(&nxt)[2][2], u32(&cxs)[4], u32(&nxs)[4]) {
    int nf = f + 1, nhc = hc;
    if (nf == 39) { nf = 0; ++nhc; }
    const bool more = (nhc < HC2);
    if (more) {  // issue next tile's 4 reg-loads + xs (consumed next tile)
      const int koff = nf * HPAD + nhc * 64;
      #pragma unroll
      for (int c = 0; c < 2; ++c) {
        nxt[c][0].s = *(const us8*)(wp0 + koff + c * 32);
        nxt[c][1].s = *(const us8*)(wp1 + koff + c * 32);
      }
      #pragma unroll
      for (int m = 0; m < 4; ++m) nxs[m] = x0pk[rs[m]][rd[m]][nf];
    }
    #pragma unroll
    for (int c = 0; c < 2; ++c)
      #pragma unroll
      for (int m = 0; m < 4; ++m) {
        HF a;
        #pragma unroll
        for (int i = 0; i < 4; ++i) a.u[i] = pkmul(hf2[m][c].u[i], cxs[m]);
        acc[m][0] = __builtin_amdgcn_mfma_f32_16x16x32_f16(a.h, cur[c][0].h, acc[m][0], 0, 0, 0);
        acc[m][1] = __builtin_amdgcn_mfma_f32_16x16x32_f16(a.h, cur[c][1].h, acc[m][1], 0, 0, 0);
      }
    if (LAYER != 0 && more && nhc != hc) {  // k64-chunk boundary: reload h frags
      #pragma unroll
      for (int m = 0; m < 4; ++m)
        #pragma unroll
        for (int c = 0; c < 2; ++c)
          hf2[m][c].s = *(const us8*)(
              &hin[(((size_t)(bbase + rs[m]) * 32 + rd[m]) << 7) + (2 * nhc + c) * 32 + g * 8]);
    }
    f = nf;
    hc = nhc;
  };

  if constexpr (NT % 2 == 1) {
    tile(frA, frB, xsA, xsB);
    for (int p = 0; p < NT / 2; ++p) {
      tile(frB, frA, xsB, xsA);
      tile(frA, frB, xsA, xsB);
    }
  } else {
    for (int p = 0; p < NT / 2; ++p) {
      tile(frA, frB, xsA, xsB);
      tile(frB, frA, xsB, xsA);
    }
  }

  __syncthreads();  // all hin reads done before any hout write (hbuf aliases)

  // ---- epilogue: relu(acc+bias); o<128 -> h for next layer; else d-sums
  float bv[2];
  #pragma unroll
  for (int nt = 0; nt < 2; ++nt) bv[nt] = bias[w * 32 + nt * 16 + l15];

  if (LAYER < 2 && w < 4) {  // h half (o in [0,128))
    #pragma unroll
    for (int m = 0; m < 4; ++m)
      #pragma unroll
      for (int nt = 0; nt < 2; ++nt) {
        int o = w * 32 + nt * 16 + l15;
        #pragma unroll
        for (int r = 0; r < 4; ++r) {
          int row = m * 16 + g * 4 + r;  // C/D: row=(lane>>4)*4+reg, col=lane&15
          int s = row >> 5, d = row & 31;
          float v = fmaxf(acc[m][nt][r] + bv[nt], 0.f);
          hout[(((bbase + s) * 32 + d) << 7) + o] = f32_to_f16u(v);
        }
      }
  } else {  // finals: sum over d per sample, store fsum[b][j]
    #pragma unroll
    for (int nt = 0; nt < 2; ++nt) {
      float sub[2] = {0.f, 0.f};
      #pragma unroll
      for (int m = 0; m < 4; ++m)
        #pragma unroll
        for (int r = 0; r < 4; ++r)
          sub[m >> 1] += fmaxf(acc[m][nt][r] + bv[nt], 0.f);
      #pragma unroll
      for (int s = 0; s < 2; ++s) {
        sub[s] += __shfl_xor(sub[s], 16);
        sub[s] += __shfl_xor(sub[s], 32);
      }
      if (lane < 16) {
        int o = w * 32 + nt * 16 + l15;
        int j = (LAYER == 0) ? (o - 128) : ((LAYER == 1) ? o : (256 + o));
        fsum[(bbase + 0) * 512 + j] = sub[0];
        fsum[(bbase + 1) * 512 + j] = sub[1];
      }
    }
  }
}

// ---------------- finalize: out[b] = fc_b + sum_j fsum[b][j]*fc_w[j] ----------
__global__ void finalize(const float* __restrict__ fsum, const float* __restrict__ fc_w,
                         const float* __restrict__ fc_b, float* __restrict__ out) {
  int b = blockIdx.x;
  int lane = threadIdx.x;  // 64
  const float* fs = fsum + (size_t)b * 512;
  float s = 0.f;
  #pragma unroll
  for (int k = 0; k < 8; ++k) {
    int j = k * 64 + lane;
    s += fs[j] * fc_w[j];
  }
  #pragma unroll
  for (int off = 32; off; off >>= 1) s += __shfl_xor(s, off);
  if (lane == 0) out[b] = s + fc_b[0];
}

extern "C" void kernel_launch(void* const* d_in, const int* in_sizes, int n_in,
                              void* d_out, int out_size, void* d_ws, size_t ws_size,
                              hipStream_t stream) {
  const float* x = (const float*)d_in[0];
  const float* W0 = (const float*)d_in[1];
  const float* b0 = (const float*)d_in[2];
  const float* W1 = (const float*)d_in[3];
  const float* b1 = (const float*)d_in[4];
  const float* W2 = (const float*)d_in[5];
  const float* b2 = (const float*)d_in[6];
  const float* fc_w = (const float*)d_in[7];
  const float* fc_b = (const float*)d_in[8];
  float* out = (float*)d_out;

  char* ws = (char*)d_ws;
  size_t oWT0 = 0;
  size_t oWT1 = oWT0 + (size_t)256 * 2496 * 2;
  size_t oWT2 = oWT1 + (size_t)256 * 4992 * 2;
  size_t oH = oWT2 + (size_t)256 * 4992 * 2;
  size_t oFS = oH + (size_t)1024 * 32 * 128 * 2;
  u16* WT0 = (u16*)(ws + oWT0);
  u16* WT1 = (u16*)(ws + oWT1);
  u16* WT2 = (u16*)(ws + oWT2);
  u16* hbuf = (u16*)(ws + oH);
  float* fsum = (float*)(ws + oFS);

  prep_wt<<<1560, 256, 0, stream>>>(W0, W1, W2, WT0, WT1, WT2);
  cin_layer<0><<<512, 512, 0, stream>>>(x, nullptr, WT0, b0, hbuf, fsum);
  cin_layer<1><<<512, 512, 0, stream>>>(x, hbuf, WT1, b1, hbuf, fsum);
  cin_layer<2><<<512, 512, 0, stream>>>(x, hbuf, WT2, b2, nullptr, fsum);
  finalize<<<1024, 64, 0, stream>>>(fsum, fc_w, fc_b, out);
}

// Round 11
// 221.391 us; speedup vs baseline: 1.9087x; 1.9087x over previous
//
#include <hip/hip_runtime.h>
#include <stdint.h>

// CIN (xDeepFM) forward, MI355X f16-MFMA implementation. Round 11:
//  - r7 shell (best: 200us) converted to 32x32x16 MFMA: halves per-FLOP
//    instruction counts (16 vs 32 MFMA/tile/wave, 4 vs 8 xs reads) and
//    improves the MFMA pipe ceiling 17% (8.07 vs 9.7 cy per 32kFLOP).
//    m-tiles = 4 samples x 32 d-rows (d = lane&31). C/D layout per m74/m101:
//    col=lane&31, row=(reg&3)+8*(reg>>2)+4*(lane>>5). A/B k-maps built
//    identically so any k-permutation cancels (r1-proven trick).
//  - everything else byte-identical r7: barrier-free K-loop (wave-private
//    wtile slices, vmcnt(4)+sched_barrier), gload_lds(16B), XOR swizzle,
//    hT/x0pk staging, 256 blocks x 512 thr.
// Layers: out[b,d,o] = relu(bias[o] + sum_{f,h'} x0[b,f,d]*h[b,h',d]*W[f*Hp+h',o])
//   layer0: Hp=39 (pad 64), layers1/2: Hp=128. B=1024, F=39, D=32, N=256.

typedef unsigned int u32;
typedef unsigned short u16;
typedef __attribute__((ext_vector_type(8))) unsigned short us8;
typedef __attribute__((ext_vector_type(8))) _Float16 half8;
typedef __attribute__((ext_vector_type(16))) float f32x16;

__device__ __forceinline__ u16 f32_to_f16u(float f) {
  union { _Float16 h; u16 u; } c;
  c.h = (_Float16)f;
  return c.u;
}
__device__ __forceinline__ u32 pkmul(u32 a, u32 b) {
  u32 r;
  asm("v_pk_mul_f16 %0, %1, %2" : "=v"(r) : "v"(a), "v"(b));
  return r;
}
__device__ __forceinline__ void gload16(const u16* g, u16* l) {
  __builtin_amdgcn_global_load_lds((const __attribute__((address_space(1))) u32*)g,
                                   (__attribute__((address_space(3))) u32*)l, 16, 0, 0);
}
__device__ __forceinline__ void wait_vm4() {
  asm volatile("s_waitcnt vmcnt(4)" ::: "memory");
  __builtin_amdgcn_sched_barrier(0);
}
__device__ __forceinline__ void wait_vm0() {
  asm volatile("s_waitcnt vmcnt(0)" ::: "memory");
  __builtin_amdgcn_sched_barrier(0);
}

// ---------------- prep: W (K,256) f32 -> WT (256, KPAD) f16, transposed ------
__global__ void prep_wt(const float* __restrict__ W0, const float* __restrict__ W1,
                        const float* __restrict__ W2, u16* __restrict__ WT0,
                        u16* __restrict__ WT1, u16* __restrict__ WT2) {
  int blk = blockIdx.x;
  const float* W;
  u16* WT;
  int KPAD, kp0;
  bool l0 = false;
  if (blk < 312) { W = W0; WT = WT0; KPAD = 2496; kp0 = blk * 8; l0 = true; }
  else if (blk < 936) { W = W1; WT = WT1; KPAD = 4992; kp0 = (blk - 312) * 8; }
  else { W = W2; WT = WT2; KPAD = 4992; kp0 = (blk - 936) * 8; }

  __shared__ u16 lds[8][257];
  int t = threadIdx.x;  // 256 = n
  #pragma unroll
  for (int kk = 0; kk < 8; ++kk) {
    int kp = kp0 + kk;
    float v;
    if (l0) {
      int f = kp >> 6, hh = kp & 63;
      v = (hh < 39) ? W[(f * 39 + hh) * 256 + t] : 0.f;
    } else {
      v = W[kp * 256 + t];
    }
    lds[kk][t] = f32_to_f16u(v);
  }
  __syncthreads();
  us8 o;
  #pragma unroll
  for (int kk = 0; kk < 8; ++kk) o[kk] = lds[kk][t];
  *(us8*)(&WT[(size_t)t * KPAD + kp0]) = o;
}

// ---------------- main layer kernel ------------------------------------------
// grid 256 x 512 threads. Block: 4 samples (M=128 = 4 m-tiles of 32 d-rows),
// 8 waves each covering all 128 rows x its own 32-col slice. K-tile = 64,
// dbuf LDS, no inner barriers. 32x32x16 f16 MFMA.
template <int LAYER>
__global__ __launch_bounds__(512, 2) void cin_layer(
    const float* __restrict__ x, const u16* __restrict__ hin,
    const u16* __restrict__ WT, const float* __restrict__ bias,
    u16* __restrict__ hout, float* __restrict__ fsum) {
  constexpr int HPAD = (LAYER == 0) ? 64 : 128;
  constexpr int HROW = HPAD + 8;
  constexpr int KPAD = 39 * HPAD;
  constexpr int HC2 = HPAD / 64;  // k64 tiles per f
  constexpr int NT = 39 * HC2;

  __shared__ __align__(16) u16 wtile[2][256 * 64];  // [n][64k] swizzled, dbuf
  __shared__ __align__(16) u16 hT[4][32][HROW];     // h^T f16 [b'][d][h']
  __shared__ u32 x0pk[4][32][41];                   // (x,x) packed f16 pairs

  const int tid = threadIdx.x;
  const int bbase = blockIdx.x * 4;

  // ---- stage x -> x0pk (+hT for layer 0)
  for (int idx = tid; idx < 4 * 1248; idx += 512) {
    int b = idx / 1248;
    int rem = idx - b * 1248;
    int f = rem >> 5, d = rem & 31;
    u16 xh = f32_to_f16u(x[(bbase + b) * 1248 + rem]);
    x0pk[b][d][f] = (u32)xh | ((u32)xh << 16);
    if (LAYER == 0) hT[b][d][f] = xh;
  }
  if (LAYER == 0) {
    for (int idx = tid; idx < 4 * 32 * 25; idx += 512) {  // zero h' in [39,64)
      int b = idx / 800;
      int rem = idx - b * 800;
      int d = rem / 25, p = rem - d * 25;
      hT[b][d][39 + p] = 0;
    }
  } else {
    for (int idx = tid; idx < 4 * 32 * 16; idx += 512) {  // h_buf f16 [b][d][128]
      int b = idx >> 9, rem = idx & 511;
      int d = rem >> 4, c = rem & 15;
      us8 v = *(const us8*)(&hin[(((bbase + b) * 32 + d) << 7) + c * 8]);
      *(us8*)(&hT[b][d][c * 8]) = v;
    }
  }

  const int lane = tid & 63;
  const int w = tid >> 6;   // wave 0..7 -> 32-col slice
  const int l31 = lane & 31;
  const int hi = lane >> 5;

  // staging per-lane source (inverse-swizzle): lane covers row n, 16B slot
  const int nloc = lane >> 3, slot = lane & 7;
  const int qq = slot ^ nloc;  // data chunk index held at this slot
  const u16* wsrc = WT + (size_t)(w * 32 + nloc) * KPAD + qq * 8;

  // B-read base (swizzled): row n = w*32 + l31; chunk q = kk*2 + hi
  const int rB = (w * 32 + l31) * 64;
  const int r7 = l31 & 7;

  f32x16 acc[4];
  #pragma unroll
  for (int m = 0; m < 4; ++m)
    #pragma unroll
    for (int r = 0; r < 16; ++r) acc[m][r] = 0.f;

  // prologue: stage tile 0 (koff=0) into buf 0
  {
    u16* dst = &wtile[0][(w * 32) * 64];
    #pragma unroll
    for (int j = 0; j < 4; ++j) gload16(wsrc + (size_t)j * 8 * KPAD, dst + j * 8 * 64);
  }
  __syncthreads();  // covers hT/x0pk ds-writes AND tile0 (vmcnt0+lgkmcnt0)

  union HF { u32 u[4]; half8 h; us8 s; };

  // k64-chunk h fragments: hf2[mt][kk] = h[s=mt, k=hc*64+kk*16+hi*8 ..+8, d=l31]
  HF hf2[4][4];
  #pragma unroll
  for (int m = 0; m < 4; ++m)
    #pragma unroll
    for (int kk = 0; kk < 4; ++kk)
      hf2[m][kk].s = *(const us8*)(&hT[m][l31][kk * 16 + hi * 8]);

  int f = 0, hc = 0;
  for (int tt = 0; tt < NT; ++tt) {
    const int buf = tt & 1;
    const bool more = (tt + 1 < NT);
    int nf = f + 1, nhc = hc;
    if (nf == 39) { nf = 0; ++nhc; }
    if (more) {  // issue next tile's 4 loads into buf^1 (wave-private rows)
      const int koff = nf * HPAD + nhc * 64;
      u16* dst = &wtile[buf ^ 1][(w * 32) * 64];
      #pragma unroll
      for (int j = 0; j < 4; ++j)
        gload16(wsrc + (size_t)j * 8 * KPAD + koff, dst + j * 8 * 64);
      wait_vm4();  // tile t's 4 loads (oldest) retired; t+1's stay in flight
    } else {
      wait_vm0();
    }
    u32 xs[4];
    #pragma unroll
    for (int m = 0; m < 4; ++m) xs[m] = x0pk[m][l31][f];
    #pragma unroll
    for (int kk = 0; kk < 4; ++kk) {
      HF b;
      b.s = *(const us8*)(&wtile[buf][rB + (((kk * 2 + hi) ^ r7) * 8)]);
      #pragma unroll
      for (int m = 0; m < 4; ++m) {
        HF a;
        #pragma unroll
        for (int i = 0; i < 4; ++i) a.u[i] = pkmul(hf2[m][kk].u[i], xs[m]);
        acc[m] = __builtin_amdgcn_mfma_f32_32x32x16_f16(a.h, b.h, acc[m], 0, 0, 0);
      }
    }
    if (more && nhc != hc) {  // chunk boundary (1x per layer1/2): reload h frags
      #pragma unroll
      for (int m = 0; m < 4; ++m)
        #pragma unroll
        for (int kk = 0; kk < 4; ++kk)
          hf2[m][kk].s = *(const us8*)(&hT[m][l31][nhc * 64 + kk * 16 + hi * 8]);
    }
    f = nf;
    hc = nhc;
  }

  // ---- epilogue: relu(acc+bias); o<128 -> h for next layer; else d-sums
  const float bv = bias[w * 32 + l31];

  if (LAYER < 2 && w < 4) {  // h half (o in [0,128))
    const int o = w * 32 + l31;
    #pragma unroll
    for (int m = 0; m < 4; ++m)
      #pragma unroll
      for (int r = 0; r < 16; ++r) {
        int d = (r & 3) + 8 * (r >> 2) + 4 * hi;  // C/D row map (m74/m101)
        float v = fmaxf(acc[m][r] + bv, 0.f);
        hout[(((bbase + m) * 32 + d) << 7) + o] = f32_to_f16u(v);
      }
  } else {  // finals: sum over d per sample, store fsum[b][j]
    #pragma unroll
    for (int m = 0; m < 4; ++m) {
      float sub = 0.f;
      #pragma unroll
      for (int r = 0; r < 16; ++r) sub += fmaxf(acc[m][r] + bv, 0.f);
      sub += __shfl_xor(sub, 32);  // combine d-halves (hi=0/1)
      if (lane < 32) {
        int o = w * 32 + l31;
        int j = (LAYER == 0) ? (o - 128) : ((LAYER == 1) ? o : (256 + o));
        fsum[(bbase + m) * 512 + j] = sub;
      }
    }
  }
}

// ---------------- finalize: out[b] = fc_b + sum_j fsum[b][j]*fc_w[j] ----------
__global__ void finalize(const float* __restrict__ fsum, const float* __restrict__ fc_w,
                         const float* __restrict__ fc_b, float* __restrict__ out) {
  int b = blockIdx.x;
  int lane = threadIdx.x;  // 64
  const float* fs = fsum + (size_t)b * 512;
  float s = 0.f;
  #pragma unroll
  for (int k = 0; k < 8; ++k) {
    int j = k * 64 + lane;
    s += fs[j] * fc_w[j];
  }
  #pragma unroll
  for (int off = 32; off; off >>= 1) s += __shfl_xor(s, off);
  if (lane == 0) out[b] = s + fc_b[0];
}

extern "C" void kernel_launch(void* const* d_in, const int* in_sizes, int n_in,
                              void* d_out, int out_size, void* d_ws, size_t ws_size,
                              hipStream_t stream) {
  const float* x = (const float*)d_in[0];
  const float* W0 = (const float*)d_in[1];
  const float* b0 = (const float*)d_in[2];
  const float* W1 = (const float*)d_in[3];
  const float* b1 = (const float*)d_in[4];
  const float* W2 = (const float*)d_in[5];
  const float* b2 = (const float*)d_in[6];
  const float* fc_w = (const float*)d_in[7];
  const float* fc_b = (const float*)d_in[8];
  float* out = (float*)d_out;

  char* ws = (char*)d_ws;
  size_t oWT0 = 0;
  size_t oWT1 = oWT0 + (size_t)256 * 2496 * 2;
  size_t oWT2 = oWT1 + (size_t)256 * 4992 * 2;
  size_t oH = oWT2 + (size_t)256 * 4992 * 2;
  size_t oFS = oH + (size_t)1024 * 32 * 128 * 2;
  u16* WT0 = (u16*)(ws + oWT0);
  u16* WT1 = (u16*)(ws + oWT1);
  u16* WT2 = (u16*)(ws + oWT2);
  u16* hbuf = (u16*)(ws + oH);
  float* fsum = (float*)(ws + oFS);

  prep_wt<<<1560, 256, 0, stream>>>(W0, W1, W2, WT0, WT1, WT2);
  cin_layer<0><<<256, 512, 0, stream>>>(x, nullptr, WT0, b0, hbuf, fsum);
  cin_layer<1><<<256, 512, 0, stream>>>(x, hbuf, WT1, b1, hbuf, fsum);
  cin_layer<2><<<256, 512, 0, stream>>>(x, hbuf, WT2, b2, nullptr, fsum);
  finalize<<<1024, 64, 0, stream>>>(fsum, fc_w, fc_b, out);
}

// Round 12
// 205.525 us; speedup vs baseline: 2.0560x; 1.0772x over previous
//
#include <hip/hip_runtime.h>
#include <stdint.h>

// CIN (xDeepFM) forward, MI355X f16-MFMA implementation. Round 12:
//  - r7 shell (best: 200us) + T5 s_setprio(1) around the pkmul+MFMA cluster
//    (waves drift barrier-free -> role diversity -> setprio pays, m191/m224
//    regime) + xs reads vectorized: 8x ds_read_b32 -> 2x ds_read_b128 from
//    xsT[16][stride 324] (16B-aligned rows, 2-way bank alias = free).
//  - everything else byte-identical r7: barrier-free K-loop (wave-private
//    wtile slices, vmcnt(4)+sched_barrier), gload_lds(16B), XOR swizzle,
//    hT/x0pk staging, 16x16x32 f16 MFMA, 256 blocks x 512 thr.
// Layers: out[b,d,o] = relu(bias[o] + sum_{f,h'} x0[b,f,d]*h[b,h',d]*W[f*Hp+h',o])
//   layer0: Hp=39 (pad 64), layers1/2: Hp=128. B=1024, F=39, D=32, N=256.

typedef unsigned int u32;
typedef unsigned short u16;
typedef __attribute__((ext_vector_type(8))) unsigned short us8;
typedef __attribute__((ext_vector_type(8))) _Float16 half8;
typedef __attribute__((ext_vector_type(4))) float f32x4;
typedef __attribute__((ext_vector_type(4))) u32 u32x4;

__device__ __forceinline__ u16 f32_to_f16u(float f) {
  union { _Float16 h; u16 u; } c;
  c.h = (_Float16)f;
  return c.u;
}
__device__ __forceinline__ u32 pkmul(u32 a, u32 b) {
  u32 r;
  asm("v_pk_mul_f16 %0, %1, %2" : "=v"(r) : "v"(a), "v"(b));
  return r;
}
__device__ __forceinline__ void gload16(const u16* g, u16* l) {
  __builtin_amdgcn_global_load_lds((const __attribute__((address_space(1))) u32*)g,
                                   (__attribute__((address_space(3))) u32*)l, 16, 0, 0);
}
__device__ __forceinline__ void wait_vm4() {
  asm volatile("s_waitcnt vmcnt(4)" ::: "memory");
  __builtin_amdgcn_sched_barrier(0);
}
__device__ __forceinline__ void wait_vm0() {
  asm volatile("s_waitcnt vmcnt(0)" ::: "memory");
  __builtin_amdgcn_sched_barrier(0);
}

// ---------------- prep: W (K,256) f32 -> WT (256, KPAD) f16, transposed ------
__global__ void prep_wt(const float* __restrict__ W0, const float* __restrict__ W1,
                        const float* __restrict__ W2, u16* __restrict__ WT0,
                        u16* __restrict__ WT1, u16* __restrict__ WT2) {
  int blk = blockIdx.x;
  const float* W;
  u16* WT;
  int KPAD, kp0;
  bool l0 = false;
  if (blk < 312) { W = W0; WT = WT0; KPAD = 2496; kp0 = blk * 8; l0 = true; }
  else if (blk < 936) { W = W1; WT = WT1; KPAD = 4992; kp0 = (blk - 312) * 8; }
  else { W = W2; WT = WT2; KPAD = 4992; kp0 = (blk - 936) * 8; }

  __shared__ u16 lds[8][257];
  int t = threadIdx.x;  // 256 = n
  #pragma unroll
  for (int kk = 0; kk < 8; ++kk) {
    int kp = kp0 + kk;
    float v;
    if (l0) {
      int f = kp >> 6, hh = kp & 63;
      v = (hh < 39) ? W[(f * 39 + hh) * 256 + t] : 0.f;
    } else {
      v = W[kp * 256 + t];
    }
    lds[kk][t] = f32_to_f16u(v);
  }
  __syncthreads();
  us8 o;
  #pragma unroll
  for (int kk = 0; kk < 8; ++kk) o[kk] = lds[kk][t];
  *(us8*)(&WT[(size_t)t * KPAD + kp0]) = o;
}

// ---------------- main layer kernel ------------------------------------------
// grid 256 x 512 threads. Block: 4 samples (M=128 rows), 8 waves each covering
// all 128 rows x its own 32-col slice. K-tile = 64, dbuf LDS, no inner barriers.
template <int LAYER>
__global__ __launch_bounds__(512, 2) void cin_layer(
    const float* __restrict__ x, const u16* __restrict__ hin,
    const u16* __restrict__ WT, const float* __restrict__ bias,
    u16* __restrict__ hout, float* __restrict__ fsum) {
  constexpr int HPAD = (LAYER == 0) ? 64 : 128;
  constexpr int HROW = HPAD + 8;
  constexpr int KPAD = 39 * HPAD;
  constexpr int HC2 = HPAD / 64;  // k64 tiles per f
  constexpr int NT = 39 * HC2;
  constexpr int XSTR = 324;  // xsT row stride (u32): 16B-aligned, 2-way banks

  __shared__ __align__(16) u16 wtile[2][256 * 64];  // [n][64k] swizzled, dbuf
  __shared__ __align__(16) u16 hT[4][32][HROW];     // h^T f16 [b'][d][h']
  __shared__ u32 x0pk[4][32][41];                   // (x,x) packed f16 pairs
  __shared__ __align__(16) u32 xsT[16 * XSTR];      // [l15][f*8 + m] packed x

  const int tid = threadIdx.x;
  const int bbase = blockIdx.x * 4;

  // ---- stage x -> x0pk (+hT for layer 0)
  for (int idx = tid; idx < 4 * 1248; idx += 512) {
    int b = idx / 1248;
    int rem = idx - b * 1248;
    int f = rem >> 5, d = rem & 31;
    u16 xh = f32_to_f16u(x[(bbase + b) * 1248 + rem]);
    x0pk[b][d][f] = (u32)xh | ((u32)xh << 16);
    if (LAYER == 0) hT[b][d][f] = xh;
  }
  // ---- stage xsT[dl][f][m] = pack(x[bbase+(m>>1)][f][(m&1)*16+dl])
  for (int idx = tid; idx < 16 * 39 * 8; idx += 512) {
    int dl = idx / 312;
    int rem = idx - dl * 312;
    int f = rem >> 3, m = rem & 7;
    u16 xh = f32_to_f16u(x[(size_t)(bbase + (m >> 1)) * 1248 + f * 32 + (m & 1) * 16 + dl]);
    xsT[dl * XSTR + f * 8 + m] = (u32)xh | ((u32)xh << 16);
  }
  if (LAYER == 0) {
    for (int idx = tid; idx < 4 * 32 * 25; idx += 512) {  // zero h' in [39,64)
      int b = idx / 800;
      int rem = idx - b * 800;
      int d = rem / 25, p = rem - d * 25;
      hT[b][d][39 + p] = 0;
    }
  } else {
    for (int idx = tid; idx < 4 * 32 * 16; idx += 512) {  // h_buf f16 [b][d][128]
      int b = idx >> 9, rem = idx & 511;
      int d = rem >> 4, c = rem & 15;
      us8 v = *(const us8*)(&hin[(((bbase + b) * 32 + d) << 7) + c * 8]);
      *(us8*)(&hT[b][d][c * 8]) = v;
    }
  }

  const int lane = tid & 63;
  const int w = tid >> 6;  // wave 0..7 -> 32-col slice
  const int l15 = lane & 15;
  const int g = lane >> 4;

  // staging per-lane source (inverse-swizzle): lane covers row n, 16B slot
  const int nloc = lane >> 3, slot = lane & 7;
  const int qq = slot ^ nloc;  // data chunk index held at this slot
  const u16* wsrc = WT + (size_t)(w * 32 + nloc) * KPAD + qq * 8;

  // B-read bases (swizzled): row n = w*32 + nt*16 + l15, n&7 == l15&7
  const int xorm = (l15 & 7) * 8;       // u16 units
  const int rB0 = (w * 32 + l15) * 64;  // nt=0 row base
  const u32* xrow = &xsT[l15 * XSTR];

  f32x4 acc[8][2];
  #pragma unroll
  for (int m = 0; m < 8; ++m)
    #pragma unroll
    for (int n = 0; n < 2; ++n) acc[m][n] = (f32x4){0.f, 0.f, 0.f, 0.f};

  // prologue: stage tile 0 (koff=0) into buf 0
  {
    u16* dst = &wtile[0][(w * 32) * 64];
    #pragma unroll
    for (int j = 0; j < 4; ++j) gload16(wsrc + (size_t)j * 8 * KPAD, dst + j * 8 * 64);
  }
  __syncthreads();  // covers hT/x0pk/xsT ds-writes AND tile0 (vmcnt0+lgkmcnt0)

  union HF { u32 u[4]; half8 h; us8 s; };

  // chunk-0 h fragments (reused across the 39-f loop)
  HF hf2[8][2];
  #pragma unroll
  for (int m = 0; m < 8; ++m)
    #pragma unroll
    for (int c = 0; c < 2; ++c)
      hf2[m][c].s = *(const us8*)(&hT[m >> 1][(m & 1) * 16 + l15][c * 32 + g * 8]);

  int f = 0, hc = 0;
  for (int tt = 0; tt < NT; ++tt) {
    const int buf = tt & 1;
    const bool more = (tt + 1 < NT);
    int nf = f + 1, nhc = hc;
    if (nf == 39) { nf = 0; ++nhc; }
    if (more) {  // issue next tile's 4 loads into buf^1 (wave-private rows)
      const int koff = nf * HPAD + nhc * 64;
      u16* dst = &wtile[buf ^ 1][(w * 32) * 64];
      #pragma unroll
      for (int j = 0; j < 4; ++j)
        gload16(wsrc + (size_t)j * 8 * KPAD + koff, dst + j * 8 * 64);
      wait_vm4();  // tile t's 4 loads (oldest) retired; t+1's stay in flight
    } else {
      wait_vm0();
    }
    // xs for all 8 m-tiles: 2 x ds_read_b128
    union { u32x4 v[2]; u32 u[8]; } xq;
    xq.v[0] = *(const u32x4*)(&xrow[f * 8]);
    xq.v[1] = *(const u32x4*)(&xrow[f * 8 + 4]);
    __builtin_amdgcn_s_setprio(1);
    #pragma unroll
    for (int c = 0; c < 2; ++c) {
      const int off = (c * 32 + g * 8) ^ xorm;
      HF b0, b1;
      b0.s = *(const us8*)(&wtile[buf][rB0 + off]);
      b1.s = *(const us8*)(&wtile[buf][rB0 + 16 * 64 + off]);
      #pragma unroll
      for (int m = 0; m < 8; ++m) {
        HF a;
        #pragma unroll
        for (int i = 0; i < 4; ++i) a.u[i] = pkmul(hf2[m][c].u[i], xq.u[m]);
        acc[m][0] = __builtin_amdgcn_mfma_f32_16x16x32_f16(a.h, b0.h, acc[m][0], 0, 0, 0);
        acc[m][1] = __builtin_amdgcn_mfma_f32_16x16x32_f16(a.h, b1.h, acc[m][1], 0, 0, 0);
      }
    }
    __builtin_amdgcn_s_setprio(0);
    if (more && nhc != hc) {  // chunk boundary (1x per layer1/2): reload h frags
      #pragma unroll
      for (int m = 0; m < 8; ++m)
        #pragma unroll
        for (int c = 0; c < 2; ++c)
          hf2[m][c].s =
              *(const us8*)(&hT[m >> 1][(m & 1) * 16 + l15][(2 * nhc + c) * 32 + g * 8]);
    }
    f = nf;
    hc = nhc;
  }

  // ---- epilogue: relu(acc+bias); o<128 -> h for next layer; else d-sums
  float bv[2];
  #pragma unroll
  for (int nt = 0; nt < 2; ++nt) bv[nt] = bias[w * 32 + nt * 16 + l15];

  if (LAYER < 2 && w < 4) {  // h half (o in [0,128))
    #pragma unroll
    for (int m = 0; m < 8; ++m)
      #pragma unroll
      for (int nt = 0; nt < 2; ++nt) {
        int o = w * 32 + nt * 16 + l15;
        #pragma unroll
        for (int r = 0; r < 4; ++r) {
          int row = m * 16 + g * 4 + r;  // C/D: row=(lane>>4)*4+reg, col=lane&15
          int s = row >> 5, d = row & 31;
          float v = fmaxf(acc[m][nt][r] + bv[nt], 0.f);
          hout[(((bbase + s) * 32 + d) << 7) + o] = f32_to_f16u(v);
        }
      }
  } else {  // finals: sum over d per sample, store fsum[b][j]
    #pragma unroll
    for (int nt = 0; nt < 2; ++nt) {
      float sub[4] = {0.f, 0.f, 0.f, 0.f};
      #pragma unroll
      for (int m = 0; m < 8; ++m)
        #pragma unroll
        for (int r = 0; r < 4; ++r)
          sub[m >> 1] += fmaxf(acc[m][nt][r] + bv[nt], 0.f);
      #pragma unroll
      for (int s = 0; s < 4; ++s) {
        sub[s] += __shfl_xor(sub[s], 16);
        sub[s] += __shfl_xor(sub[s], 32);
      }
      if (lane < 16) {
        int o = w * 32 + nt * 16 + l15;
        int j = (LAYER == 0) ? (o - 128) : ((LAYER == 1) ? o : (256 + o));
        #pragma unroll
        for (int s = 0; s < 4; ++s) fsum[(bbase + s) * 512 + j] = sub[s];
      }
    }
  }
}

// ---------------- finalize: out[b] = fc_b + sum_j fsum[b][j]*fc_w[j] ----------
__global__ void finalize(const float* __restrict__ fsum, const float* __restrict__ fc_w,
                         const float* __restrict__ fc_b, float* __restrict__ out) {
  int b = blockIdx.x;
  int lane = threadIdx.x;  // 64
  const float* fs = fsum + (size_t)b * 512;
  float s = 0.f;
  #pragma unroll
  for (int k = 0; k < 8; ++k) {
    int j = k * 64 + lane;
    s += fs[j] * fc_w[j];
  }
  #pragma unroll
  for (int off = 32; off; off >>= 1) s += __shfl_xor(s, off);
  if (lane == 0) out[b] = s + fc_b[0];
}

extern "C" void kernel_launch(void* const* d_in, const int* in_sizes, int n_in,
                              void* d_out, int out_size, void* d_ws, size_t ws_size,
                              hipStream_t stream) {
  const float* x = (const float*)d_in[0];
  const float* W0 = (const float*)d_in[1];
  const float* b0 = (const float*)d_in[2];
  const float* W1 = (const float*)d_in[3];
  const float* b1 = (const float*)d_in[4];
  const float* W2 = (const float*)d_in[5];
  const float* b2 = (const float*)d_in[6];
  const float* fc_w = (const float*)d_in[7];
  const float* fc_b = (const float*)d_in[8];
  float* out = (float*)d_out;

  char* ws = (char*)d_ws;
  size_t oWT0 = 0;
  size_t oWT1 = oWT0 + (size_t)256 * 2496 * 2;
  size_t oWT2 = oWT1 + (size_t)256 * 4992 * 2;
  size_t oH = oWT2 + (size_t)256 * 4992 * 2;
  size_t oFS = oH + (size_t)1024 * 32 * 128 * 2;
  u16* WT0 = (u16*)(ws + oWT0);
  u16* WT1 = (u16*)(ws + oWT1);
  u16* WT2 = (u16*)(ws + oWT2);
  u16* hbuf = (u16*)(ws + oH);
  float* fsum = (float*)(ws + oFS);

  prep_wt<<<1560, 256, 0, stream>>>(W0, W1, W2, WT0, WT1, WT2);
  cin_layer<0><<<256, 512, 0, stream>>>(x, nullptr, WT0, b0, hbuf, fsum);
  cin_layer<1><<<256, 512, 0, stream>>>(x, hbuf, WT1, b1, hbuf, fsum);
  cin_layer<2><<<256, 512, 0, stream>>>(x, hbuf, WT2, b2, nullptr, fsum);
  finalize<<<1024, 64, 0, stream>>>(fsum, fc_w, fc_b, out);
}

// Round 13
// 196.751 us; speedup vs baseline: 2.1477x; 1.0446x over previous
//
#include <hip/hip_runtime.h>
#include <stdint.h>

// CIN (xDeepFM) forward, MI355X f16-MFMA implementation. Round 13:
//  - xs path moved OUT of LDS: prep_xg pre-transposes x into global
//    xg[bgroup][l15][f][m] u16; per tile each lane does ONE
//    global_load_dwordx4 (issued a tile ahead) and v_pk_mul_f16 with
//    VOP3P op_sel broadcasts the f16 scalar (no unpack, no LDS).
//    x0pk LDS deleted (-21KB). LDS/tile now = 4 B-reads + W-write.
//    Rationale: five schedules pinned at ~2600cy/tile; accounting says
//    CU-shared LDS unit (~1200cy/tile) serializes with MFMA (1242cy).
//  - shell = r9 (proven): barrier-free K-loop, wave-private wtile slices,
//    gload_lds(16B), XOR swizzle, reg-pipelined fr, 256 blocks x 512 thr.
// Layers: out[b,d,o] = relu(bias[o] + sum_{f,h'} x0[b,f,d]*h[b,h',d]*W[f*Hp+h',o])
//   layer0: Hp=39 (pad 64), layers1/2: Hp=128. B=1024, F=39, D=32, N=256.

typedef unsigned int u32;
typedef unsigned short u16;
typedef __attribute__((ext_vector_type(8))) unsigned short us8;
typedef __attribute__((ext_vector_type(8))) _Float16 half8;
typedef __attribute__((ext_vector_type(4))) float f32x4;

__device__ __forceinline__ u16 f32_to_f16u(float f) {
  union { _Float16 h; u16 u; } c;
  c.h = (_Float16)f;
  return c.u;
}
// a.{lo,hi} * broadcast(b.lo)
__device__ __forceinline__ u32 pkmul_blo(u32 a, u32 b) {
  u32 r;
  asm("v_pk_mul_f16 %0, %1, %2 op_sel:[0,0] op_sel_hi:[1,0]" : "=v"(r) : "v"(a), "v"(b));
  return r;
}
// a.{lo,hi} * broadcast(b.hi)
__device__ __forceinline__ u32 pkmul_bhi(u32 a, u32 b) {
  u32 r;
  asm("v_pk_mul_f16 %0, %1, %2 op_sel:[0,1] op_sel_hi:[1,1]" : "=v"(r) : "v"(a), "v"(b));
  return r;
}
__device__ __forceinline__ void gload16(const u16* g, u16* l) {
  __builtin_amdgcn_global_load_lds((const __attribute__((address_space(1))) u32*)g,
                                   (__attribute__((address_space(3))) u32*)l, 16, 0, 0);
}
__device__ __forceinline__ void wait_vm0_sb() {
  asm volatile("s_waitcnt vmcnt(0)" ::: "memory");
  __builtin_amdgcn_sched_barrier(0);
}

// ---------------- prep: W (K,256) f32 -> WT (256, KPAD) f16, transposed ------
__global__ void prep_wt(const float* __restrict__ W0, const float* __restrict__ W1,
                        const float* __restrict__ W2, u16* __restrict__ WT0,
                        u16* __restrict__ WT1, u16* __restrict__ WT2) {
  int blk = blockIdx.x;
  const float* W;
  u16* WT;
  int KPAD, kp0;
  bool l0 = false;
  if (blk < 312) { W = W0; WT = WT0; KPAD = 2496; kp0 = blk * 8; l0 = true; }
  else if (blk < 936) { W = W1; WT = WT1; KPAD = 4992; kp0 = (blk - 312) * 8; }
  else { W = W2; WT = WT2; KPAD = 4992; kp0 = (blk - 936) * 8; }

  __shared__ u16 lds[8][257];
  int t = threadIdx.x;  // 256 = n
  #pragma unroll
  for (int kk = 0; kk < 8; ++kk) {
    int kp = kp0 + kk;
    float v;
    if (l0) {
      int f = kp >> 6, hh = kp & 63;
      v = (hh < 39) ? W[(f * 39 + hh) * 256 + t] : 0.f;
    } else {
      v = W[kp * 256 + t];
    }
    lds[kk][t] = f32_to_f16u(v);
  }
  __syncthreads();
  us8 o;
  #pragma unroll
  for (int kk = 0; kk < 8; ++kk) o[kk] = lds[kk][t];
  *(us8*)(&WT[(size_t)t * KPAD + kp0]) = o;
}

// ---------------- prep: x -> xg[bgroup][dl(16)][f(39)][m(8)] f16 -------------
// xg value at (bb,dl,f,m) = f16(x[bb*4 + (m>>1)][f][(m&1)*16 + dl])
__global__ void prep_xg(const float* __restrict__ x, u16* __restrict__ xg) {
  int bb = blockIdx.x;  // 0..255
  int t = threadIdx.x;  // 256
  for (int idx = t; idx < 4992; idx += 256) {
    int dl = idx / 312;
    int rem = idx - dl * 312;
    int f = rem >> 3, m = rem & 7;
    float v = x[(size_t)(bb * 4 + (m >> 1)) * 1248 + f * 32 + (m & 1) * 16 + dl];
    xg[(size_t)bb * 4992 + idx] = f32_to_f16u(v);
  }
}

// ---------------- main layer kernel ------------------------------------------
// grid 256 x 512 threads. Block: 4 samples (M=128 rows), 8 waves each covering
// all 128 rows x its own 32-col slice. K-tile = 64, dbuf LDS, no inner barriers.
template <int LAYER>
__global__ __launch_bounds__(512, 2) void cin_layer(
    const float* __restrict__ x, const u16* __restrict__ hin,
    const u16* __restrict__ WT, const u16* __restrict__ xg,
    const float* __restrict__ bias, u16* __restrict__ hout,
    float* __restrict__ fsum) {
  constexpr int HPAD = (LAYER == 0) ? 64 : 128;
  constexpr int HROW = HPAD + 8;
  constexpr int KPAD = 39 * HPAD;
  constexpr int HC2 = HPAD / 64;  // k64 tiles per f
  constexpr int NT = 39 * HC2;

  __shared__ __align__(16) u16 wtile[2][256 * 64];  // [n][64k] swizzled, dbuf
  __shared__ __align__(16) u16 hT[4][32][HROW];     // h^T f16 [b'][d][h']

  const int tid = threadIdx.x;
  const int bbase = blockIdx.x * 4;

  // ---- stage hT (from x for layer 0, from hbuf otherwise)
  if (LAYER == 0) {
    for (int idx = tid; idx < 4 * 1248; idx += 512) {
      int b = idx / 1248;
      int rem = idx - b * 1248;
      int f = rem >> 5, d = rem & 31;
      hT[b][d][f] = f32_to_f16u(x[(bbase + b) * 1248 + rem]);
    }
    for (int idx = tid; idx < 4 * 32 * 25; idx += 512) {  // zero h' in [39,64)
      int b = idx / 800;
      int rem = idx - b * 800;
      int d = rem / 25, p = rem - d * 25;
      hT[b][d][39 + p] = 0;
    }
  } else {
    for (int idx = tid; idx < 4 * 32 * 16; idx += 512) {  // h_buf f16 [b][d][128]
      int b = idx >> 9, rem = idx & 511;
      int d = rem >> 4, c = rem & 15;
      us8 v = *(const us8*)(&hin[(((bbase + b) * 32 + d) << 7) + c * 8]);
      *(us8*)(&hT[b][d][c * 8]) = v;
    }
  }

  const int lane = tid & 63;
  const int w = tid >> 6;  // wave 0..7 -> 32-col slice
  const int l15 = lane & 15;
  const int g = lane >> 4;

  // staging per-lane source (inverse-swizzle): lane covers row n, 16B slot
  const int nloc = lane >> 3, slot = lane & 7;
  const int qq = slot ^ nloc;  // data chunk index held at this slot
  const u16* wsrc = WT + (size_t)(w * 32 + nloc) * KPAD + qq * 8;

  // B-read bases (swizzled): row n = w*32 + nt*16 + l15, n&7 == l15&7
  const int xorm = (l15 & 7) * 8;       // u16 units
  const int rB0 = (w * 32 + l15) * 64;  // nt=0 row base
  const u16* xrow = xg + (size_t)blockIdx.x * 4992 + l15 * 312;

  f32x4 acc[8][2];
  #pragma unroll
  for (int m = 0; m < 8; ++m)
    #pragma unroll
    for (int n = 0; n < 2; ++n) acc[m][n] = (f32x4){0.f, 0.f, 0.f, 0.f};

  // prologue: stage tile 0 (koff=0) into buf 0
  {
    u16* dst = &wtile[0][(w * 32) * 64];
    #pragma unroll
    for (int j = 0; j < 4; ++j) gload16(wsrc + (size_t)j * 8 * KPAD, dst + j * 8 * 64);
  }
  __syncthreads();  // covers hT ds-writes AND tile0 (vmcnt0+lgkmcnt0)

  union HF { u32 u[4]; half8 h; us8 s; };
  union XQ { u32 u[4]; us8 s; };

  // chunk-0 h fragments (reused across the 39-f loop)
  HF hf2[8][2];
  #pragma unroll
  for (int m = 0; m < 8; ++m)
    #pragma unroll
    for (int c = 0; c < 2; ++c)
      hf2[m][c].s = *(const us8*)(&hT[m >> 1][(m & 1) * 16 + l15][c * 32 + g * 8]);

  // preload tile-0 B-fragments (from LDS) and xs (from global)
  HF fr[2][2];
  XQ xqA, xqB;
  #pragma unroll
  for (int c = 0; c < 2; ++c) {
    const int off = (c * 32 + g * 8) ^ xorm;
    fr[c][0].s = *(const us8*)(&wtile[0][rB0 + off]);
    fr[c][1].s = *(const us8*)(&wtile[0][rB0 + 16 * 64 + off]);
  }
  xqA.s = *(const us8*)(xrow);  // f=0

  int f = 0, hc = 0, tt = 0;

#define TILE_BODY(XC, XN)                                                          \
  {                                                                                \
    const int buf = tt & 1;                                                        \
    const bool more = (tt + 1 < NT);                                               \
    int nf = f + 1, nhc = hc;                                                      \
    if (nf == 39) { nf = 0; ++nhc; }                                               \
    if (more) {                                                                    \
      const int koff = nf * HPAD + nhc * 64;                                       \
      u16* dst = &wtile[buf ^ 1][(w * 32) * 64];                                   \
      _Pragma("unroll")                                                            \
      for (int j = 0; j < 4; ++j)                                                  \
        gload16(wsrc + (size_t)j * 8 * KPAD + koff, dst + j * 8 * 64);             \
      XN.s = *(const us8*)(xrow + nf * 8);                                         \
      __builtin_amdgcn_sched_barrier(0);                                           \
    }                                                                              \
    _Pragma("unroll")                                                              \
    for (int c = 0; c < 2; ++c) {                                                  \
      _Pragma("unroll")                                                            \
      for (int m = 0; m < 8; ++m) {                                                \
        HF a;                                                                      \
        _Pragma("unroll")                                                          \
        for (int i = 0; i < 4; ++i)                                                \
          a.u[i] = (m & 1) ? pkmul_bhi(hf2[m][c].u[i], XC.u[m >> 1])               \
                           : pkmul_blo(hf2[m][c].u[i], XC.u[m >> 1]);              \
        acc[m][0] = __builtin_amdgcn_mfma_f32_16x16x32_f16(a.h, fr[c][0].h,        \
                                                           acc[m][0], 0, 0, 0);    \
        acc[m][1] = __builtin_amdgcn_mfma_f32_16x16x32_f16(a.h, fr[c][1].h,        \
                                                           acc[m][1], 0, 0, 0);    \
      }                                                                            \
    }                                                                              \
    if (more) {                                                                    \
      wait_vm0_sb();                                                               \
      _Pragma("unroll")                                                            \
      for (int c = 0; c < 2; ++c) {                                                \
        const int off = (c * 32 + g * 8) ^ xorm;                                   \
        fr[c][0].s = *(const us8*)(&wtile[buf ^ 1][rB0 + off]);                    \
        fr[c][1].s = *(const us8*)(&wtile[buf ^ 1][rB0 + 16 * 64 + off]);          \
      }                                                                            \
      if (nhc != hc) {                                                             \
        _Pragma("unroll")                                                          \
        for (int m = 0; m < 8; ++m)                                                \
          _Pragma("unroll")                                                        \
          for (int c = 0; c < 2; ++c)                                              \
            hf2[m][c].s = *(const us8*)(                                           \
                &hT[m >> 1][(m & 1) * 16 + l15][(2 * nhc + c) * 32 + g * 8]);      \
      }                                                                            \
    }                                                                              \
    f = nf;                                                                        \
    hc = nhc;                                                                      \
    ++tt;                                                                          \
  }

  for (int p = 0; p < NT / 2; ++p) {
    TILE_BODY(xqA, xqB);
    TILE_BODY(xqB, xqA);
  }
  if (NT & 1) TILE_BODY(xqA, xqB);
#undef TILE_BODY

  // ---- epilogue: relu(acc+bias); o<128 -> h for next layer; else d-sums
  float bv[2];
  #pragma unroll
  for (int nt = 0; nt < 2; ++nt) bv[nt] = bias[w * 32 + nt * 16 + l15];

  if (LAYER < 2 && w < 4) {  // h half (o in [0,128))
    #pragma unroll
    for (int m = 0; m < 8; ++m)
      #pragma unroll
      for (int nt = 0; nt < 2; ++nt) {
        int o = w * 32 + nt * 16 + l15;
        #pragma unroll
        for (int r = 0; r < 4; ++r) {
          int row = m * 16 + g * 4 + r;  // C/D: row=(lane>>4)*4+reg, col=lane&15
          int s = row >> 5, d = row & 31;
          float v = fmaxf(acc[m][nt][r] + bv[nt], 0.f);
          hout[(((bbase + s) * 32 + d) << 7) + o] = f32_to_f16u(v);
        }
      }
  } else {  // finals: sum over d per sample, store fsum[b][j]
    #pragma unroll
    for (int nt = 0; nt < 2; ++nt) {
      float sub[4] = {0.f, 0.f, 0.f, 0.f};
      #pragma unroll
      for (int m = 0; m < 8; ++m)
        #pragma unroll
        for (int r = 0; r < 4; ++r)
          sub[m >> 1] += fmaxf(acc[m][nt][r] + bv[nt], 0.f);
      #pragma unroll
      for (int s = 0; s < 4; ++s) {
        sub[s] += __shfl_xor(sub[s], 16);
        sub[s] += __shfl_xor(sub[s], 32);
      }
      if (lane < 16) {
        int o = w * 32 + nt * 16 + l15;
        int j = (LAYER == 0) ? (o - 128) : ((LAYER == 1) ? o : (256 + o));
        #pragma unroll
        for (int s = 0; s < 4; ++s) fsum[(bbase + s) * 512 + j] = sub[s];
      }
    }
  }
}

// ---------------- finalize: out[b] = fc_b + sum_j fsum[b][j]*fc_w[j] ----------
__global__ void finalize(const float* __restrict__ fsum, const float* __restrict__ fc_w,
                         const float* __restrict__ fc_b, float* __restrict__ out) {
  int b = blockIdx.x;
  int lane = threadIdx.x;  // 64
  const float* fs = fsum + (size_t)b * 512;
  float s = 0.f;
  #pragma unroll
  for (int k = 0; k < 8; ++k) {
    int j = k * 64 + lane;
    s += fs[j] * fc_w[j];
  }
  #pragma unroll
  for (int off = 32; off; off >>= 1) s += __shfl_xor(s, off);
  if (lane == 0) out[b] = s + fc_b[0];
}

extern "C" void kernel_launch(void* const* d_in, const int* in_sizes, int n_in,
                              void* d_out, int out_size, void* d_ws, size_t ws_size,
                              hipStream_t stream) {
  const float* x = (const float*)d_in[0];
  const float* W0 = (const float*)d_in[1];
  const float* b0 = (const float*)d_in[2];
  const float* W1 = (const float*)d_in[3];
  const float* b1 = (const float*)d_in[4];
  const float* W2 = (const float*)d_in[5];
  const float* b2 = (const float*)d_in[6];
  const float* fc_w = (const float*)d_in[7];
  const float* fc_b = (const float*)d_in[8];
  float* out = (float*)d_out;

  char* ws = (char*)d_ws;
  size_t oWT0 = 0;
  size_t oWT1 = oWT0 + (size_t)256 * 2496 * 2;
  size_t oWT2 = oWT1 + (size_t)256 * 4992 * 2;
  size_t oH = oWT2 + (size_t)256 * 4992 * 2;
  size_t oFS = oH + (size_t)1024 * 32 * 128 * 2;
  size_t oXG = oFS + (size_t)1024 * 512 * 4;
  u16* WT0 = (u16*)(ws + oWT0);
  u16* WT1 = (u16*)(ws + oWT1);
  u16* WT2 = (u16*)(ws + oWT2);
  u16* hbuf = (u16*)(ws + oH);
  float* fsum = (float*)(ws + oFS);
  u16* xg = (u16*)(ws + oXG);  // 256*4992*2 = 2.56 MB

  prep_wt<<<1560, 256, 0, stream>>>(W0, W1, W2, WT0, WT1, WT2);
  prep_xg<<<256, 256, 0, stream>>>(x, xg);
  cin_layer<0><<<256, 512, 0, stream>>>(x, nullptr, WT0, xg, b0, hbuf, fsum);
  cin_layer<1><<<256, 512, 0, stream>>>(x, hbuf, WT1, xg, b1, hbuf, fsum);
  cin_layer<2><<<256, 512, 0, stream>>>(x, hbuf, WT2, xg, b2, nullptr, fsum);
  finalize<<<1024, 64, 0, stream>>>(fsum, fc_w, fc_b, out);
}

// Round 14
// 193.345 us; speedup vs baseline: 2.1855x; 1.0176x over previous
//
#include <hip/hip_runtime.h>
#include <stdint.h>

// CIN (xDeepFM) forward, MI355X f16-MFMA implementation. Round 14:
//  - WAVE-STAGGERED K-ORDER: wave w starts its (order-independent) f-loop at
//    offset (w*5)%39 within each k64 chunk. All K-loop state is wave-private
//    (wtile rows, acc, xs row, hf2), so waves drift ~5 tiles out of phase ->
//    breaks the convoy effect (all 8 waves hitting LDS phase together while
//    the matrix pipe idles, then all hitting MFMA together while LDS idles)
//    that pinned r7-r13 at ~42-45% MfmaUtil.
//  - setprio(1) around the MFMA cluster (now has real role diversity).
//  - everything else byte-identical r13 (best: 196.8us): xg global xs path
//    with op_sel broadcast, barrier-free K-loop, gload_lds(16B), XOR swizzle,
//    reg-pipelined fr, 256 blocks x 512 thr.
// Layers: out[b,d,o] = relu(bias[o] + sum_{f,h'} x0[b,f,d]*h[b,h',d]*W[f*Hp+h',o])
//   layer0: Hp=39 (pad 64), layers1/2: Hp=128. B=1024, F=39, D=32, N=256.

typedef unsigned int u32;
typedef unsigned short u16;
typedef __attribute__((ext_vector_type(8))) unsigned short us8;
typedef __attribute__((ext_vector_type(8))) _Float16 half8;
typedef __attribute__((ext_vector_type(4))) float f32x4;

__device__ __forceinline__ u16 f32_to_f16u(float f) {
  union { _Float16 h; u16 u; } c;
  c.h = (_Float16)f;
  return c.u;
}
// a.{lo,hi} * broadcast(b.lo)
__device__ __forceinline__ u32 pkmul_blo(u32 a, u32 b) {
  u32 r;
  asm("v_pk_mul_f16 %0, %1, %2 op_sel:[0,0] op_sel_hi:[1,0]" : "=v"(r) : "v"(a), "v"(b));
  return r;
}
// a.{lo,hi} * broadcast(b.hi)
__device__ __forceinline__ u32 pkmul_bhi(u32 a, u32 b) {
  u32 r;
  asm("v_pk_mul_f16 %0, %1, %2 op_sel:[0,1] op_sel_hi:[1,1]" : "=v"(r) : "v"(a), "v"(b));
  return r;
}
__device__ __forceinline__ void gload16(const u16* g, u16* l) {
  __builtin_amdgcn_global_load_lds((const __attribute__((address_space(1))) u32*)g,
                                   (__attribute__((address_space(3))) u32*)l, 16, 0, 0);
}
__device__ __forceinline__ void wait_vm0_sb() {
  asm volatile("s_waitcnt vmcnt(0)" ::: "memory");
  __builtin_amdgcn_sched_barrier(0);
}

// ---------------- prep: W (K,256) f32 -> WT (256, KPAD) f16, transposed ------
__global__ void prep_wt(const float* __restrict__ W0, const float* __restrict__ W1,
                        const float* __restrict__ W2, u16* __restrict__ WT0,
                        u16* __restrict__ WT1, u16* __restrict__ WT2) {
  int blk = blockIdx.x;
  const float* W;
  u16* WT;
  int KPAD, kp0;
  bool l0 = false;
  if (blk < 312) { W = W0; WT = WT0; KPAD = 2496; kp0 = blk * 8; l0 = true; }
  else if (blk < 936) { W = W1; WT = WT1; KPAD = 4992; kp0 = (blk - 312) * 8; }
  else { W = W2; WT = WT2; KPAD = 4992; kp0 = (blk - 936) * 8; }

  __shared__ u16 lds[8][257];
  int t = threadIdx.x;  // 256 = n
  #pragma unroll
  for (int kk = 0; kk < 8; ++kk) {
    int kp = kp0 + kk;
    float v;
    if (l0) {
      int f = kp >> 6, hh = kp & 63;
      v = (hh < 39) ? W[(f * 39 + hh) * 256 + t] : 0.f;
    } else {
      v = W[kp * 256 + t];
    }
    lds[kk][t] = f32_to_f16u(v);
  }
  __syncthreads();
  us8 o;
  #pragma unroll
  for (int kk = 0; kk < 8; ++kk) o[kk] = lds[kk][t];
  *(us8*)(&WT[(size_t)t * KPAD + kp0]) = o;
}

// ---------------- prep: x -> xg[bgroup][dl(16)][f(39)][m(8)] f16 -------------
// xg value at (bb,dl,f,m) = f16(x[bb*4 + (m>>1)][f][(m&1)*16 + dl])
__global__ void prep_xg(const float* __restrict__ x, u16* __restrict__ xg) {
  int bb = blockIdx.x;  // 0..255
  int t = threadIdx.x;  // 256
  for (int idx = t; idx < 4992; idx += 256) {
    int dl = idx / 312;
    int rem = idx - dl * 312;
    int f = rem >> 3, m = rem & 7;
    float v = x[(size_t)(bb * 4 + (m >> 1)) * 1248 + f * 32 + (m & 1) * 16 + dl];
    xg[(size_t)bb * 4992 + idx] = f32_to_f16u(v);
  }
}

// ---------------- main layer kernel ------------------------------------------
// grid 256 x 512 threads. Block: 4 samples (M=128 rows), 8 waves each covering
// all 128 rows x its own 32-col slice. K-tile = 64, dbuf LDS, no inner barriers.
// Wave w iterates f in rotated order starting at (w*5)%39.
template <int LAYER>
__global__ __launch_bounds__(512, 2) void cin_layer(
    const float* __restrict__ x, const u16* __restrict__ hin,
    const u16* __restrict__ WT, const u16* __restrict__ xg,
    const float* __restrict__ bias, u16* __restrict__ hout,
    float* __restrict__ fsum) {
  constexpr int HPAD = (LAYER == 0) ? 64 : 128;
  constexpr int HROW = HPAD + 8;
  constexpr int KPAD = 39 * HPAD;
  constexpr int HC2 = HPAD / 64;  // k64 tiles per f
  constexpr int NT = 39 * HC2;

  __shared__ __align__(16) u16 wtile[2][256 * 64];  // [n][64k] swizzled, dbuf
  __shared__ __align__(16) u16 hT[4][32][HROW];     // h^T f16 [b'][d][h']

  const int tid = threadIdx.x;
  const int bbase = blockIdx.x * 4;

  // ---- stage hT (from x for layer 0, from hbuf otherwise)
  if (LAYER == 0) {
    for (int idx = tid; idx < 4 * 1248; idx += 512) {
      int b = idx / 1248;
      int rem = idx - b * 1248;
      int f = rem >> 5, d = rem & 31;
      hT[b][d][f] = f32_to_f16u(x[(bbase + b) * 1248 + rem]);
    }
    for (int idx = tid; idx < 4 * 32 * 25; idx += 512) {  // zero h' in [39,64)
      int b = idx / 800;
      int rem = idx - b * 800;
      int d = rem / 25, p = rem - d * 25;
      hT[b][d][39 + p] = 0;
    }
  } else {
    for (int idx = tid; idx < 4 * 32 * 16; idx += 512) {  // h_buf f16 [b][d][128]
      int b = idx >> 9, rem = idx & 511;
      int d = rem >> 4, c = rem & 15;
      us8 v = *(const us8*)(&hin[(((bbase + b) * 32 + d) << 7) + c * 8]);
      *(us8*)(&hT[b][d][c * 8]) = v;
    }
  }

  const int lane = tid & 63;
  const int w = tid >> 6;  // wave 0..7 -> 32-col slice
  const int l15 = lane & 15;
  const int g = lane >> 4;
  const int off = (w * 5) % 39;  // per-wave f-rotation (stagger)

  // staging per-lane source (inverse-swizzle): lane covers row n, 16B slot
  const int nloc = lane >> 3, slot = lane & 7;
  const int qq = slot ^ nloc;  // data chunk index held at this slot
  const u16* wsrc = WT + (size_t)(w * 32 + nloc) * KPAD + qq * 8;

  // B-read bases (swizzled): row n = w*32 + nt*16 + l15, n&7 == l15&7
  const int xorm = (l15 & 7) * 8;       // u16 units
  const int rB0 = (w * 32 + l15) * 64;  // nt=0 row base
  const u16* xrow = xg + (size_t)blockIdx.x * 4992 + l15 * 312;

  f32x4 acc[8][2];
  #pragma unroll
  for (int m = 0; m < 8; ++m)
    #pragma unroll
    for (int n = 0; n < 2; ++n) acc[m][n] = (f32x4){0.f, 0.f, 0.f, 0.f};

  // prologue: stage this wave's first tile (f=off, hc=0) into buf 0
  {
    const int koff0 = off * HPAD;
    u16* dst = &wtile[0][(w * 32) * 64];
    #pragma unroll
    for (int j = 0; j < 4; ++j)
      gload16(wsrc + (size_t)j * 8 * KPAD + koff0, dst + j * 8 * 64);
  }
  __syncthreads();  // covers hT ds-writes AND tile0 (vmcnt0+lgkmcnt0)

  union HF { u32 u[4]; half8 h; us8 s; };
  union XQ { u32 u[4]; us8 s; };

  // chunk-0 h fragments (reused across the 39-f loop)
  HF hf2[8][2];
  #pragma unroll
  for (int m = 0; m < 8; ++m)
    #pragma unroll
    for (int c = 0; c < 2; ++c)
      hf2[m][c].s = *(const us8*)(&hT[m >> 1][(m & 1) * 16 + l15][c * 32 + g * 8]);

  // preload tile-0 B-fragments (from LDS) and xs (from global)
  HF fr[2][2];
  XQ xqA, xqB;
  #pragma unroll
  for (int c = 0; c < 2; ++c) {
    const int offb = (c * 32 + g * 8) ^ xorm;
    fr[c][0].s = *(const us8*)(&wtile[0][rB0 + offb]);
    fr[c][1].s = *(const us8*)(&wtile[0][rB0 + 16 * 64 + offb]);
  }
  xqA.s = *(const us8*)(xrow + off * 8);  // f=off

  int fi = 0, f = off, hc = 0, tt = 0;

#define TILE_BODY(XC, XN)                                                          \
  {                                                                                \
    const int buf = tt & 1;                                                        \
    const bool more = (tt + 1 < NT);                                               \
    int nfi = fi + 1, nf = f + 1, nhc = hc;                                        \
    if (nfi == 39) { nfi = 0; nf = off; ++nhc; }                                   \
    else if (nf == 39) { nf = 0; }                                                 \
    if (more) {                                                                    \
      const int koff = nf * HPAD + nhc * 64;                                       \
      u16* dst = &wtile[buf ^ 1][(w * 32) * 64];                                   \
      _Pragma("unroll")                                                            \
      for (int j = 0; j < 4; ++j)                                                  \
        gload16(wsrc + (size_t)j * 8 * KPAD + koff, dst + j * 8 * 64);             \
      XN.s = *(const us8*)(xrow + nf * 8);                                         \
      __builtin_amdgcn_sched_barrier(0);                                           \
    }                                                                              \
    __builtin_amdgcn_s_setprio(1);                                                 \
    _Pragma("unroll")                                                              \
    for (int c = 0; c < 2; ++c) {                                                  \
      _Pragma("unroll")                                                            \
      for (int m = 0; m < 8; ++m) {                                                \
        HF a;                                                                      \
        _Pragma("unroll")                                                          \
        for (int i = 0; i < 4; ++i)                                                \
          a.u[i] = (m & 1) ? pkmul_bhi(hf2[m][c].u[i], XC.u[m >> 1])               \
                           : pkmul_blo(hf2[m][c].u[i], XC.u[m >> 1]);              \
        acc[m][0] = __builtin_amdgcn_mfma_f32_16x16x32_f16(a.h, fr[c][0].h,        \
                                                           acc[m][0], 0, 0, 0);    \
        acc[m][1] = __builtin_amdgcn_mfma_f32_16x16x32_f16(a.h, fr[c][1].h,        \
                                                           acc[m][1], 0, 0, 0);    \
      }                                                                            \
    }                                                                              \
    __builtin_amdgcn_s_setprio(0);                                                 \
    if (more) {                                                                    \
      wait_vm0_sb();                                                               \
      _Pragma("unroll")                                                            \
      for (int c = 0; c < 2; ++c) {                                                \
        const int offb = (c * 32 + g * 8) ^ xorm;                                  \
        fr[c][0].s = *(const us8*)(&wtile[buf ^ 1][rB0 + offb]);                   \
        fr[c][1].s = *(const us8*)(&wtile[buf ^ 1][rB0 + 16 * 64 + offb]);         \
      }                                                                            \
      if (nhc != hc) {                                                             \
        _Pragma("unroll")                                                          \
        for (int m = 0; m < 8; ++m)                                                \
          _Pragma("unroll")                                                        \
          for (int c = 0; c < 2; ++c)                                              \
            hf2[m][c].s = *(const us8*)(                                           \
                &hT[m >> 1][(m & 1) * 16 + l15][(2 * nhc + c) * 32 + g * 8]);      \
      }                                                                            \
    }                                                                              \
    fi = nfi;                                                                      \
    f = nf;                                                                        \
    hc = nhc;                                                                      \
    ++tt;                                                                          \
  }

  for (int p = 0; p < NT / 2; ++p) {
    TILE_BODY(xqA, xqB);
    TILE_BODY(xqB, xqA);
  }
  if (NT & 1) TILE_BODY(xqA, xqB);
#undef TILE_BODY

  // ---- epilogue: relu(acc+bias); o<128 -> h for next layer; else d-sums
  float bv[2];
  #pragma unroll
  for (int nt = 0; nt < 2; ++nt) bv[nt] = bias[w * 32 + nt * 16 + l15];

  if (LAYER < 2 && w < 4) {  // h half (o in [0,128))
    #pragma unroll
    for (int m = 0; m < 8; ++m)
      #pragma unroll
      for (int nt = 0; nt < 2; ++nt) {
        int o = w * 32 + nt * 16 + l15;
        #pragma unroll
        for (int r = 0; r < 4; ++r) {
          int row = m * 16 + g * 4 + r;  // C/D: row=(lane>>4)*4+reg, col=lane&15
          int s = row >> 5, d = row & 31;
          float v = fmaxf(acc[m][nt][r] + bv[nt], 0.f);
          hout[(((bbase + s) * 32 + d) << 7) + o] = f32_to_f16u(v);
        }
      }
  } else {  // finals: sum over d per sample, store fsum[b][j]
    #pragma unroll
    for (int nt = 0; nt < 2; ++nt) {
      float sub[4] = {0.f, 0.f, 0.f, 0.f};
      #pragma unroll
      for (int m = 0; m < 8; ++m)
        #pragma unroll
        for (int r = 0; r < 4; ++r)
          sub[m >> 1] += fmaxf(acc[m][nt][r] + bv[nt], 0.f);
      #pragma unroll
      for (int s = 0; s < 4; ++s) {
        sub[s] += __shfl_xor(sub[s], 16);
        sub[s] += __shfl_xor(sub[s], 32);
      }
      if (lane < 16) {
        int o = w * 32 + nt * 16 + l15;
        int j = (LAYER == 0) ? (o - 128) : ((LAYER == 1) ? o : (256 + o));
        #pragma unroll
        for (int s = 0; s < 4; ++s) fsum[(bbase + s) * 512 + j] = sub[s];
      }
    }
  }
}

// ---------------- finalize: out[b] = fc_b + sum_j fsum[b][j]*fc_w[j] ----------
__global__ void finalize(const float* __restrict__ fsum, const float* __restrict__ fc_w,
                         const float* __restrict__ fc_b, float* __restrict__ out) {
  int b = blockIdx.x;
  int lane = threadIdx.x;  // 64
  const float* fs = fsum + (size_t)b * 512;
  float s = 0.f;
  #pragma unroll
  for (int k = 0; k < 8; ++k) {
    int j = k * 64 + lane;
    s += fs[j] * fc_w[j];
  }
  #pragma unroll
  for (int off = 32; off; off >>= 1) s += __shfl_xor(s, off);
  if (lane == 0) out[b] = s + fc_b[0];
}

extern "C" void kernel_launch(void* const* d_in, const int* in_sizes, int n_in,
                              void* d_out, int out_size, void* d_ws, size_t ws_size,
                              hipStream_t stream) {
  const float* x = (const float*)d_in[0];
  const float* W0 = (const float*)d_in[1];
  const float* b0 = (const float*)d_in[2];
  const float* W1 = (const float*)d_in[3];
  const float* b1 = (const float*)d_in[4];
  const float* W2 = (const float*)d_in[5];
  const float* b2 = (const float*)d_in[6];
  const float* fc_w = (const float*)d_in[7];
  const float* fc_b = (const float*)d_in[8];
  float* out = (float*)d_out;

  char* ws = (char*)d_ws;
  size_t oWT0 = 0;
  size_t oWT1 = oWT0 + (size_t)256 * 2496 * 2;
  size_t oWT2 = oWT1 + (size_t)256 * 4992 * 2;
  size_t oH = oWT2 + (size_t)256 * 4992 * 2;
  size_t oFS = oH + (size_t)1024 * 32 * 128 * 2;
  size_t oXG = oFS + (size_t)1024 * 512 * 4;
  u16* WT0 = (u16*)(ws + oWT0);
  u16* WT1 = (u16*)(ws + oWT1);
  u16* WT2 = (u16*)(ws + oWT2);
  u16* hbuf = (u16*)(ws + oH);
  float* fsum = (float*)(ws + oFS);
  u16* xg = (u16*)(ws + oXG);  // 256*4992*2 = 2.56 MB

  prep_wt<<<1560, 256, 0, stream>>>(W0, W1, W2, WT0, WT1, WT2);
  prep_xg<<<256, 256, 0, stream>>>(x, xg);
  cin_layer<0><<<256, 512, 0, stream>>>(x, nullptr, WT0, xg, b0, hbuf, fsum);
  cin_layer<1><<<256, 512, 0, stream>>>(x, hbuf, WT1, xg, b1, hbuf, fsum);
  cin_layer<2><<<256, 512, 0, stream>>>(x, hbuf, WT2, xg, b2, nullptr, fsum);
  finalize<<<1024, 64, 0, stream>>>(fsum, fc_w, fc_b, out);
}